// Round 2
// baseline (907.804 us; speedup 1.0000x reference)
//
#include <hip/hip_runtime.h>

typedef _Float16 f16;
typedef _Float16 f16x4 __attribute__((ext_vector_type(4)));
typedef _Float16 f16x8 __attribute__((ext_vector_type(8)));
typedef float f32x4 __attribute__((ext_vector_type(4)));

#define DEVI __device__ __forceinline__

static constexpr int CAP = 64;   // slots per row; P(deg>64 | lambda=16) ~ 1e-19

DEVI f16x8 cvt8(float4 a, float4 b) {
  f16x8 r;
  r[0] = (f16)a.x; r[1] = (f16)a.y; r[2] = (f16)a.z; r[3] = (f16)a.w;
  r[4] = (f16)b.x; r[5] = (f16)b.y; r[6] = (f16)b.z; r[7] = (f16)b.w;
  return r;
}

// ---------------- W transpose + cast: WT[n][k] = (f16)W[k][n] ----------------
__global__ __launch_bounds__(256)
void prep_w(const float* __restrict__ W1, const float* __restrict__ W2,
            const float* __restrict__ W3, f16* __restrict__ WT1,
            f16* __restrict__ WT2, f16* __restrict__ WT3) {
  int t = blockIdx.x * 256 + threadIdx.x;
  if (t < 131072) {                       // W1: 512x256 -> WT1: 256x512
    int n = t >> 9, k = t & 511;
    WT1[t] = (f16)W1[k * 256 + n];
  } else if (t < 131072 + 65536) {        // W2: 256x256 -> WT2: 256x256
    int u = t - 131072; int n = u >> 8, k = u & 255;
    WT2[u] = (f16)W2[k * 256 + n];
  } else if (t < 131072 + 65536 + 16384) {// W3: 256x64 -> WT3: 64x256
    int u = t - 131072 - 65536; int n = u >> 8, k = u & 255;
    WT3[u] = (f16)W3[k * 64 + n];
  }
}

// ---------------- bucket build: slots[r][p] = (col, val) ----------------
__global__ __launch_bounds__(256)
void build_slots(const int* __restrict__ row, const int* __restrict__ col,
                 const float* __restrict__ vals, int* __restrict__ cnt,
                 int2* __restrict__ slots, int E) {
  int e = blockIdx.x * 256 + threadIdx.x;
  if (e >= E) return;
  int r = row[e];
  int p = atomicAdd(&cnt[r], 1);
  if (p < CAP) slots[(size_t)r * CAP + p] = make_int2(col[e], __float_as_int(vals[e]));
}

// ---------------- GEMM, no LDS, no barriers ----------------
// C[M][N](f16) = A[M][K] @ WT[N][K]^T + bias.
// 4 waves/block; WN waves split N; each wave owns 32 rows x NT*16 cols.
// A and B fragments loaded straight from global (B is L2-resident: <=256KB).
// A-frag: lane holds A[m=l16][k=quad*8+j]; quads of a wave jointly cover
// 128 contiguous bytes per row -> fully coalesced.
template <int NT, int WN, int KI, bool AF32>
__global__ __launch_bounds__(256, 3)
void gemm_direct(const void* __restrict__ Ap, const f16* __restrict__ WT,
                 const float* __restrict__ bias, f16* __restrict__ C,
                 int M, int N) {
  constexpr int K = KI * 32;
  const int tid = threadIdx.x;
  const int wave = tid >> 6, lane = tid & 63;
  const int quad = lane >> 4, l16 = lane & 15;
  const int wn = (WN == 1) ? 0 : (wave & 1);
  const int wm = (WN == 1) ? wave : (wave >> 1);
  constexpr int RPB = (4 / WN) * 32;               // rows per block
  const int r0 = blockIdx.x * RPB + wm * 32;
  const int n0 = wn * (NT * 16);

  f32x4 acc[2][NT];
#pragma unroll
  for (int mt = 0; mt < 2; ++mt)
#pragma unroll
    for (int nt = 0; nt < NT; ++nt) {
      f32x4 z = {0.f, 0.f, 0.f, 0.f};
      acc[mt][nt] = z;
    }

  const int ar0 = min(r0 + l16, M - 1);
  const int ar1 = min(r0 + 16 + l16, M - 1);

#pragma unroll 2
  for (int kb = 0; kb < KI; ++kb) {
    const int k0 = kb * 32 + quad * 8;
    f16x8 af[2];
    if constexpr (AF32) {
      const float* Af = (const float*)Ap;
      const float4* p0 = (const float4*)(Af + (size_t)ar0 * K + k0);
      const float4* p1 = (const float4*)(Af + (size_t)ar1 * K + k0);
      float4 u0 = p0[0], u1 = p0[1];
      float4 v0 = p1[0], v1 = p1[1];
      af[0] = cvt8(u0, u1);
      af[1] = cvt8(v0, v1);
    } else {
      const f16* Ah = (const f16*)Ap;
      af[0] = *(const f16x8*)(Ah + (size_t)ar0 * K + k0);
      af[1] = *(const f16x8*)(Ah + (size_t)ar1 * K + k0);
    }
    f16x8 bf[NT];
#pragma unroll
    for (int nt = 0; nt < NT; ++nt)
      bf[nt] = *(const f16x8*)(WT + (size_t)(n0 + nt * 16 + l16) * K + k0);
#pragma unroll
    for (int mt = 0; mt < 2; ++mt)
#pragma unroll
      for (int nt = 0; nt < NT; ++nt)
        acc[mt][nt] = __builtin_amdgcn_mfma_f32_16x16x32_f16(af[mt], bf[nt], acc[mt][nt], 0, 0, 0);
  }

  // epilogue: + bias, store f16 (C/D layout: col=l16, row=quad*4+r)
  float bv[NT];
#pragma unroll
  for (int nt = 0; nt < NT; ++nt)
    bv[nt] = bias[n0 + nt * 16 + l16];
#pragma unroll
  for (int mt = 0; mt < 2; ++mt) {
#pragma unroll
    for (int nt = 0; nt < NT; ++nt) {
      const int colg = n0 + nt * 16 + l16;
#pragma unroll
      for (int r = 0; r < 4; ++r) {
        int grow = r0 + mt * 16 + quad * 4 + r;
        if (grow < M)
          C[(size_t)grow * N + colg] = (f16)(acc[mt][nt][r] + bv[nt]);
      }
    }
  }
}

// ---------------- SpMM (F=256) + ReLU ----------------
// One wave per output row; 2 edges concurrently (32 lanes x f16x8 each),
// 4-deep unroll -> 8 gathers in flight; xor-32 shuffle combine.
__global__ __launch_bounds__(256)
void spmm_relu256(const f16* __restrict__ T, const int2* __restrict__ slots,
                  const int* __restrict__ cnt, f16* __restrict__ H, int nrows) {
  const int wave = threadIdx.x >> 6, lane = threadIdx.x & 63;
  const int i = blockIdx.x * 4 + wave;
  if (i >= nrows) return;
  const int c = min(cnt[i], CAP);
  const int2* sl = slots + (size_t)i * CAP;
  const int half = lane >> 5, fl = lane & 31;

  float a[8];
#pragma unroll
  for (int k = 0; k < 8; ++k) a[k] = 0.f;

  int j = 0;
  for (; j + 8 <= c; j += 8) {
    int2 e0 = sl[j + half], e1 = sl[j + 2 + half];
    int2 e2 = sl[j + 4 + half], e3 = sl[j + 6 + half];
    f16x8 u0 = *(const f16x8*)(T + (size_t)e0.x * 256 + fl * 8);
    f16x8 u1 = *(const f16x8*)(T + (size_t)e1.x * 256 + fl * 8);
    f16x8 u2 = *(const f16x8*)(T + (size_t)e2.x * 256 + fl * 8);
    f16x8 u3 = *(const f16x8*)(T + (size_t)e3.x * 256 + fl * 8);
    float v0 = __int_as_float(e0.y), v1 = __int_as_float(e1.y);
    float v2 = __int_as_float(e2.y), v3 = __int_as_float(e3.y);
#pragma unroll
    for (int k = 0; k < 8; ++k)
      a[k] += v0 * (float)u0[k] + v1 * (float)u1[k] + v2 * (float)u2[k] + v3 * (float)u3[k];
  }
  for (; j < c; j += 2) {
    int jj = j + half;
    int2 e = sl[min(jj, c - 1)];
    float v = (jj < c) ? __int_as_float(e.y) : 0.f;
    f16x8 u = *(const f16x8*)(T + (size_t)e.x * 256 + fl * 8);
#pragma unroll
    for (int k = 0; k < 8; ++k) a[k] += v * (float)u[k];
  }
#pragma unroll
  for (int k = 0; k < 8; ++k) a[k] += __shfl_xor(a[k], 32, 64);
  if (half == 0) {
    f16x8 o;
#pragma unroll
    for (int k = 0; k < 8; ++k) o[k] = (f16)fmaxf(a[k], 0.f);
    *(f16x8*)(H + (size_t)i * 256 + fl * 8) = o;
  }
}

// ---------------- SpMM (F=64), fp32 out, no activation ----------------
// 4 edges concurrently (16 lanes x f16x4 each), 2-deep unroll.
__global__ __launch_bounds__(256)
void spmm_out64(const f16* __restrict__ T, const int2* __restrict__ slots,
                const int* __restrict__ cnt, float* __restrict__ out, int nrows) {
  const int wave = threadIdx.x >> 6, lane = threadIdx.x & 63;
  const int i = blockIdx.x * 4 + wave;
  if (i >= nrows) return;
  const int c = min(cnt[i], CAP);
  const int2* sl = slots + (size_t)i * CAP;
  const int sub = lane >> 4, fl = lane & 15;

  float a[4];
#pragma unroll
  for (int k = 0; k < 4; ++k) a[k] = 0.f;

  int j = 0;
  for (; j + 8 <= c; j += 8) {
    int2 e0 = sl[j + sub], e1 = sl[j + 4 + sub];
    f16x4 u0 = *(const f16x4*)(T + (size_t)e0.x * 64 + fl * 4);
    f16x4 u1 = *(const f16x4*)(T + (size_t)e1.x * 64 + fl * 4);
    float v0 = __int_as_float(e0.y), v1 = __int_as_float(e1.y);
#pragma unroll
    for (int k = 0; k < 4; ++k) a[k] += v0 * (float)u0[k] + v1 * (float)u1[k];
  }
  for (; j < c; j += 4) {
    int jj = j + sub;
    int2 e = sl[min(jj, c - 1)];
    float v = (jj < c) ? __int_as_float(e.y) : 0.f;
    f16x4 u = *(const f16x4*)(T + (size_t)e.x * 64 + fl * 4);
#pragma unroll
    for (int k = 0; k < 4; ++k) a[k] += v * (float)u[k];
  }
#pragma unroll
  for (int k = 0; k < 4; ++k) {
    a[k] += __shfl_xor(a[k], 16, 64);
    a[k] += __shfl_xor(a[k], 32, 64);
  }
  if (sub == 0) {
    float4 o = make_float4(a[0], a[1], a[2], a[3]);
    *(float4*)(out + (size_t)i * 64 + fl * 4) = o;
  }
}

extern "C" void kernel_launch(void* const* d_in, const int* in_sizes, int n_in,
                              void* d_out, int out_size, void* d_ws, size_t ws_size,
                              hipStream_t stream) {
  const float* x    = (const float*)d_in[0];
  const int*   row  = (const int*)d_in[1];
  const int*   col  = (const int*)d_in[2];
  const float* vals = (const float*)d_in[3];
  const float* W1   = (const float*)d_in[4];
  const float* b1   = (const float*)d_in[5];
  const float* W2   = (const float*)d_in[6];
  const float* b2   = (const float*)d_in[7];
  const float* W3   = (const float*)d_in[8];
  const float* b3   = (const float*)d_in[9];
  float* out = (float*)d_out;

  const int N = in_sizes[0] / 512;   // 100000
  const int E = in_sizes[1];         // 1600000

  // workspace layout (~153 MiB total)
  char* ws = (char*)d_ws;
  const size_t MiB = 1ull << 20;
  int*  cnt   = (int*)ws;                   // 0.4 MB
  int2* slots = (int2*)(ws + 1 * MiB);      // N*64*8 = 51.2 MB
  f16*  WT1   = (f16*)(ws + 52 * MiB);      // 0.26 MB
  f16*  WT2   = WT1 + 256 * 512;
  f16*  WT3   = WT2 + 256 * 256;
  f16*  T     = (f16*)(ws + 53 * MiB);      // N*256*2 = 51.2 MB
  f16*  H     = (f16*)(ws + 104 * MiB);     // N*256*2 = 51.2 MB

  hipMemsetAsync(cnt, 0, (size_t)N * sizeof(int), stream);
  prep_w<<<(131072 + 65536 + 16384 + 255) / 256, 256, 0, stream>>>(W1, W2, W3, WT1, WT2, WT3);
  build_slots<<<(E + 255) / 256, 256, 0, stream>>>(row, col, vals, cnt, slots, E);

  const int g12 = (N + 63) / 64;    // WN=2: 64 rows per block
  const int g3  = (N + 127) / 128;  // WN=1: 128 rows per block
  const int gs  = (N + 3) / 4;

  // layer 1: K=512
  gemm_direct<8, 2, 16, true><<<g12, 256, 0, stream>>>(x, WT1, b1, T, N, 256);
  spmm_relu256<<<gs, 256, 0, stream>>>(T, slots, cnt, H, N);
  // layer 2: K=256
  gemm_direct<8, 2, 8, false><<<g12, 256, 0, stream>>>(H, WT2, b2, T, N, 256);
  spmm_relu256<<<gs, 256, 0, stream>>>(T, slots, cnt, H, N);
  // layer 3: K=256, N=64
  gemm_direct<4, 1, 8, false><<<g3, 256, 0, stream>>>(H, WT3, b3, T, N, 64);
  spmm_out64<<<gs, 256, 0, stream>>>(T, slots, cnt, out, N);
}

// Round 3
// 831.790 us; speedup vs baseline: 1.0914x; 1.0914x over previous
//
#include <hip/hip_runtime.h>

typedef _Float16 f16;
typedef _Float16 f16x4 __attribute__((ext_vector_type(4)));
typedef _Float16 f16x8 __attribute__((ext_vector_type(8)));
typedef float f32x4 __attribute__((ext_vector_type(4)));

#define DEVI __device__ __forceinline__

static constexpr int CAP = 64;   // slots per row; P(deg>64 | lambda=16) ~ 1e-19

DEVI void g2l16(const void* g, void* l) {
  __builtin_amdgcn_global_load_lds(
      (const __attribute__((address_space(1))) void*)g,
      (__attribute__((address_space(3))) void*)l, 16, 0, 0);
}

DEVI f16x8 cvt8(float4 a, float4 b) {
  f16x8 r;
  r[0] = (f16)a.x; r[1] = (f16)a.y; r[2] = (f16)a.z; r[3] = (f16)a.w;
  r[4] = (f16)b.x; r[5] = (f16)b.y; r[6] = (f16)b.z; r[7] = (f16)b.w;
  return r;
}

// ---------------- W transpose + cast: WT[n][k] = (f16)W[k][n] ----------------
__global__ __launch_bounds__(256)
void prep_w(const float* __restrict__ W1, const float* __restrict__ W2,
            const float* __restrict__ W3, f16* __restrict__ WT1,
            f16* __restrict__ WT2, f16* __restrict__ WT3) {
  int t = blockIdx.x * 256 + threadIdx.x;
  if (t < 131072) {                       // W1: 512x256 -> WT1: 256x512
    int n = t >> 9, k = t & 511;
    WT1[t] = (f16)W1[k * 256 + n];
  } else if (t < 131072 + 65536) {        // W2: 256x256 -> WT2: 256x256
    int u = t - 131072; int n = u >> 8, k = u & 255;
    WT2[u] = (f16)W2[k * 256 + n];
  } else if (t < 131072 + 65536 + 16384) {// W3: 256x64 -> WT3: 64x256
    int u = t - 131072 - 65536; int n = u >> 8, k = u & 255;
    WT3[u] = (f16)W3[k * 64 + n];
  }
}

// ---------------- bucket build: slots[r][p] = (col, val) ----------------
__global__ __launch_bounds__(256)
void build_slots(const int* __restrict__ row, const int* __restrict__ col,
                 const float* __restrict__ vals, int* __restrict__ cnt,
                 int2* __restrict__ slots, int E) {
  int e = blockIdx.x * 256 + threadIdx.x;
  if (e >= E) return;
  int r = row[e];
  int p = atomicAdd(&cnt[r], 1);
  if (p < CAP) slots[(size_t)r * CAP + p] = make_int2(col[e], __float_as_int(vals[e]));
}

// ---------------- GEMM with LDS, fragment-major layout, global_load_lds ----
// C[M][N](f16) = A[M][K] @ WT[N][K]^T + bias.
// Block: RPB rows x BN cols, 4 waves (WN split N, 4/WN split M).
// LDS layout (per 16-row block): [k-chunk][row16] x 16B -> fragment
// ds_read_b128 has consecutive lanes at 16B stride = conflict-free.
// Staged with global_load_lds: LDS dest is wave-uniform base + lane*16.
template <int NT, int WN, int KI, bool AF32>
__global__ __launch_bounds__(256)
void gemm_lds(const void* __restrict__ Ap, const f16* __restrict__ WT,
              const float* __restrict__ bias, f16* __restrict__ C,
              int M, int N) {
  constexpr int K = KI * 32;
  constexpr int RPB = (4 / WN) * 32;   // rows per block
  constexpr int BN = WN * NT * 16;     // cols per block
  __shared__ alignas(16) char AsB[RPB * 32 * (AF32 ? 4 : 2)];
  __shared__ alignas(16) char BsB[BN * 32 * 2];

  const int tid = threadIdx.x;
  const int wave = tid >> 6, lane = tid & 63;
  const int quad = lane >> 4, l16 = lane & 15;
  const int wn = (WN == 1) ? 0 : (wave & 1);
  const int wm = (WN == 1) ? wave : (wave >> 1);
  const int r0 = blockIdx.x * RPB;

  f32x4 acc[2][NT];
#pragma unroll
  for (int mt = 0; mt < 2; ++mt)
#pragma unroll
    for (int nt = 0; nt < NT; ++nt) {
      f32x4 z = {0.f, 0.f, 0.f, 0.f};
      acc[mt][nt] = z;
    }

  for (int kb = 0; kb < KI; ++kb) {
    // ---- stage A ----
    if constexpr (AF32) {
      // RPB=64 rows x 32 floats = 8KB = 8 insts (2/wave).
      const float* Af = (const float*)Ap;
      const int rowg = min(r0 + wave * 16 + l16, M - 1);
#pragma unroll
      for (int t = 0; t < 2; ++t) {
        const float* gp = Af + (size_t)rowg * K + kb * 32 + (t * 4 + quad) * 4;
        g2l16(gp, AsB + wave * 2048 + t * 1024);
      }
    } else {
      const f16* Ah = (const f16*)Ap;
#pragma unroll
      for (int t = 0; t < RPB / 64; ++t) {
        const int blk = wave * (RPB / 64) + t;
        const int rowg = min(r0 + blk * 16 + l16, M - 1);
        const f16* gp = Ah + (size_t)rowg * K + kb * 32 + quad * 8;
        g2l16(gp, AsB + blk * 1024);
      }
    }
    // ---- stage B (n is always fully in range: BN==N) ----
#pragma unroll
    for (int t = 0; t < BN / 64; ++t) {
      const int blk = wave * (BN / 64) + t;
      const int n = blk * 16 + l16;
      const f16* gp = WT + (size_t)n * K + kb * 32 + quad * 8;
      g2l16(gp, BsB + blk * 1024);
    }
    __syncthreads();

    // ---- fragments ----
    f16x8 af[2];
#pragma unroll
    for (int mt = 0; mt < 2; ++mt) {
      const int blk = wm * 2 + mt;
      if constexpr (AF32) {
        const float4* p = (const float4*)(AsB + blk * 2048);
        float4 a0 = p[quad * 32 + l16];
        float4 a1 = p[quad * 32 + 16 + l16];
        af[mt] = cvt8(a0, a1);
      } else {
        af[mt] = *(const f16x8*)(AsB + blk * 1024 + (quad * 16 + l16) * 16);
      }
    }
    f16x8 bf[NT];
#pragma unroll
    for (int nt = 0; nt < NT; ++nt) {
      const int blk = wn * NT + nt;
      bf[nt] = *(const f16x8*)(BsB + blk * 1024 + (quad * 16 + l16) * 16);
    }
#pragma unroll
    for (int mt = 0; mt < 2; ++mt)
#pragma unroll
      for (int nt = 0; nt < NT; ++nt)
        acc[mt][nt] = __builtin_amdgcn_mfma_f32_16x16x32_f16(af[mt], bf[nt], acc[mt][nt], 0, 0, 0);
    __syncthreads();
  }

  // ---- epilogue: + bias, store f16 (C/D: col=l16, row=quad*4+r) ----
  float bv[NT];
#pragma unroll
  for (int nt = 0; nt < NT; ++nt)
    bv[nt] = bias[wn * NT * 16 + nt * 16 + l16];
#pragma unroll
  for (int mt = 0; mt < 2; ++mt) {
#pragma unroll
    for (int nt = 0; nt < NT; ++nt) {
      const int colg = wn * NT * 16 + nt * 16 + l16;
#pragma unroll
      for (int r = 0; r < 4; ++r) {
        const int grow = r0 + wm * 32 + mt * 16 + quad * 4 + r;
        if (grow < M)
          C[(size_t)grow * N + colg] = (f16)(acc[mt][nt][r] + bv[nt]);
      }
    }
  }
}

// ---------------- SpMM (F=256) + ReLU ----------------
// One wave per output row; 2 edges concurrently (32 lanes x f16x8 each),
// 8-deep unroll -> 8 gathers in flight; xor-32 shuffle combine.
__global__ __launch_bounds__(256)
void spmm_relu256(const f16* __restrict__ T, const int2* __restrict__ slots,
                  const int* __restrict__ cnt, f16* __restrict__ H, int nrows) {
  const int wave = threadIdx.x >> 6, lane = threadIdx.x & 63;
  const int i = blockIdx.x * 4 + wave;
  if (i >= nrows) return;
  const int c = min(cnt[i], CAP);
  const int2* sl = slots + (size_t)i * CAP;
  const int half = lane >> 5, fl = lane & 31;

  float a[8];
#pragma unroll
  for (int k = 0; k < 8; ++k) a[k] = 0.f;

  int j = 0;
  for (; j + 16 <= c; j += 16) {
    int2 e[8];
#pragma unroll
    for (int t = 0; t < 8; ++t) e[t] = sl[j + 2 * t + half];
    f16x8 u[8];
#pragma unroll
    for (int t = 0; t < 8; ++t)
      u[t] = *(const f16x8*)(T + (size_t)e[t].x * 256 + fl * 8);
#pragma unroll
    for (int t = 0; t < 8; ++t) {
      const float v = __int_as_float(e[t].y);
#pragma unroll
      for (int k = 0; k < 8; ++k) a[k] += v * (float)u[t][k];
    }
  }
  for (; j + 8 <= c; j += 8) {
    int2 e0 = sl[j + half], e1 = sl[j + 2 + half];
    int2 e2 = sl[j + 4 + half], e3 = sl[j + 6 + half];
    f16x8 u0 = *(const f16x8*)(T + (size_t)e0.x * 256 + fl * 8);
    f16x8 u1 = *(const f16x8*)(T + (size_t)e1.x * 256 + fl * 8);
    f16x8 u2 = *(const f16x8*)(T + (size_t)e2.x * 256 + fl * 8);
    f16x8 u3 = *(const f16x8*)(T + (size_t)e3.x * 256 + fl * 8);
    float v0 = __int_as_float(e0.y), v1 = __int_as_float(e1.y);
    float v2 = __int_as_float(e2.y), v3 = __int_as_float(e3.y);
#pragma unroll
    for (int k = 0; k < 8; ++k)
      a[k] += v0 * (float)u0[k] + v1 * (float)u1[k] + v2 * (float)u2[k] + v3 * (float)u3[k];
  }
  for (; j < c; j += 2) {
    const int jj = j + half;
    int2 e = sl[min(jj, c - 1)];
    const float v = (jj < c) ? __int_as_float(e.y) : 0.f;
    f16x8 u = *(const f16x8*)(T + (size_t)e.x * 256 + fl * 8);
#pragma unroll
    for (int k = 0; k < 8; ++k) a[k] += v * (float)u[k];
  }
#pragma unroll
  for (int k = 0; k < 8; ++k) a[k] += __shfl_xor(a[k], 32, 64);
  if (half == 0) {
    f16x8 o;
#pragma unroll
    for (int k = 0; k < 8; ++k) o[k] = (f16)fmaxf(a[k], 0.f);
    *(f16x8*)(H + (size_t)i * 256 + fl * 8) = o;
  }
}

// ---------------- SpMM (F=64), fp32 out, no activation ----------------
__global__ __launch_bounds__(256)
void spmm_out64(const f16* __restrict__ T, const int2* __restrict__ slots,
                const int* __restrict__ cnt, float* __restrict__ out, int nrows) {
  const int wave = threadIdx.x >> 6, lane = threadIdx.x & 63;
  const int i = blockIdx.x * 4 + wave;
  if (i >= nrows) return;
  const int c = min(cnt[i], CAP);
  const int2* sl = slots + (size_t)i * CAP;
  const int sub = lane >> 4, fl = lane & 15;

  float a[4];
#pragma unroll
  for (int k = 0; k < 4; ++k) a[k] = 0.f;

  int j = 0;
  for (; j + 16 <= c; j += 16) {
    int2 e[4];
#pragma unroll
    for (int t = 0; t < 4; ++t) e[t] = sl[j + 4 * t + sub];
    f16x4 u[4];
#pragma unroll
    for (int t = 0; t < 4; ++t)
      u[t] = *(const f16x4*)(T + (size_t)e[t].x * 64 + fl * 4);
#pragma unroll
    for (int t = 0; t < 4; ++t) {
      const float v = __int_as_float(e[t].y);
#pragma unroll
      for (int k = 0; k < 4; ++k) a[k] += v * (float)u[t][k];
    }
  }
  for (; j < c; j += 4) {
    const int jj = j + sub;
    int2 e = sl[min(jj, c - 1)];
    const float v = (jj < c) ? __int_as_float(e.y) : 0.f;
    f16x4 u = *(const f16x4*)(T + (size_t)e.x * 64 + fl * 4);
#pragma unroll
    for (int k = 0; k < 4; ++k) a[k] += v * (float)u[k];
  }
#pragma unroll
  for (int k = 0; k < 4; ++k) {
    a[k] += __shfl_xor(a[k], 16, 64);
    a[k] += __shfl_xor(a[k], 32, 64);
  }
  if (sub == 0) {
    float4 o = make_float4(a[0], a[1], a[2], a[3]);
    *(float4*)(out + (size_t)i * 64 + fl * 4) = o;
  }
}

extern "C" void kernel_launch(void* const* d_in, const int* in_sizes, int n_in,
                              void* d_out, int out_size, void* d_ws, size_t ws_size,
                              hipStream_t stream) {
  const float* x    = (const float*)d_in[0];
  const int*   row  = (const int*)d_in[1];
  const int*   col  = (const int*)d_in[2];
  const float* vals = (const float*)d_in[3];
  const float* W1   = (const float*)d_in[4];
  const float* b1   = (const float*)d_in[5];
  const float* W2   = (const float*)d_in[6];
  const float* b2   = (const float*)d_in[7];
  const float* W3   = (const float*)d_in[8];
  const float* b3   = (const float*)d_in[9];
  float* out = (float*)d_out;

  const int N = in_sizes[0] / 512;   // 100000
  const int E = in_sizes[1];         // 1600000

  // workspace layout (~153 MiB total)
  char* ws = (char*)d_ws;
  const size_t MiB = 1ull << 20;
  int*  cnt   = (int*)ws;                   // 0.4 MB
  int2* slots = (int2*)(ws + 1 * MiB);      // N*64*8 = 51.2 MB
  f16*  WT1   = (f16*)(ws + 52 * MiB);      // 0.26 MB
  f16*  WT2   = WT1 + 256 * 512;
  f16*  WT3   = WT2 + 256 * 256;
  f16*  T     = (f16*)(ws + 53 * MiB);      // N*256*2 = 51.2 MB
  f16*  H     = (f16*)(ws + 104 * MiB);     // N*256*2 = 51.2 MB

  hipMemsetAsync(cnt, 0, (size_t)N * sizeof(int), stream);
  prep_w<<<(131072 + 65536 + 16384 + 255) / 256, 256, 0, stream>>>(W1, W2, W3, WT1, WT2, WT3);
  build_slots<<<(E + 255) / 256, 256, 0, stream>>>(row, col, vals, cnt, slots, E);

  const int g12 = (N + 63) / 64;    // 64 rows/block, full 256 cols
  const int g3  = (N + 127) / 128;  // 128 rows/block, 64 cols
  const int gs  = (N + 3) / 4;

  // layer 1: K=512, fp32 A
  gemm_lds<8, 2, 16, true><<<g12, 256, 0, stream>>>(x, WT1, b1, T, N, 256);
  spmm_relu256<<<gs, 256, 0, stream>>>(T, slots, cnt, H, N);
  // layer 2: K=256, f16 A
  gemm_lds<8, 2, 8, false><<<g12, 256, 0, stream>>>(H, WT2, b2, T, N, 256);
  spmm_relu256<<<gs, 256, 0, stream>>>(T, slots, cnt, H, N);
  // layer 3: K=256, N=64, f16 A
  gemm_lds<4, 1, 8, false><<<g3, 256, 0, stream>>>(H, WT3, b3, T, N, 64);
  spmm_out64<<<gs, 256, 0, stream>>>(T, slots, cnt, out, N);
}